// Round 12
// baseline (135.571 us; speedup 1.0000x reference)
//
#include <hip/hip_runtime.h>
#include <hip/hip_bf16.h>
#include <cstdint>

#define NB   64
#define CIN  1024
#define HWSP 196
#define MTOT 12544
#define PL   256
#define COUT 1024

using f32x4 = __attribute__((ext_vector_type(4))) float;
using s16x8 = __attribute__((ext_vector_type(8))) short;

static __device__ __forceinline__ short f2bf(float f) {
  union { __hip_bfloat16 h; short s; } u;
  u.h = __float2bfloat16(f);
  return u.s;
}
static __device__ __forceinline__ float bf2f(short s) {
  union { float f; unsigned u; } x;
  x.u = ((unsigned)(unsigned short)s) << 16;
  return x.f;
}

static __device__ __forceinline__ void gload16(const void* g, void* l) {
  __builtin_amdgcn_global_load_lds((const __attribute__((address_space(1))) void*)g,
                                   (__attribute__((address_space(3))) void*)l, 16, 0, 0);
}

// ------------- merged prep: x-transpose | weight cast/reorder | stats zero ---
__global__ __launch_bounds__(256) void k_prep(const float* __restrict__ x,
                                              const float* __restrict__ w1,
                                              const float* __restrict__ w2,
                                              const float* __restrict__ w3,
                                              short* __restrict__ xb,
                                              short* __restrict__ w1b,
                                              short* __restrict__ w2b,
                                              short* __restrict__ w3b,
                                              float* __restrict__ statszero) {
  const int bid = blockIdx.x;
  if (bid < 2048) {
    __shared__ float tile[32][197];
    const int n = bid >> 5;
    const int c0 = (bid & 31) * 32;
    for (int idx = threadIdx.x; idx < 32 * 196; idx += 256) {
      int cl = idx / 196, hw = idx % 196;
      tile[cl][hw] = x[((size_t)(n * CIN + c0 + cl)) * HWSP + hw];
    }
    __syncthreads();
    for (int idx = threadIdx.x; idx < 196 * 32; idx += 256) {
      int hw = idx >> 5, cl = idx & 31;
      xb[((size_t)(n * HWSP + hw)) * CIN + c0 + cl] = f2bf(tile[cl][hw]);
    }
  } else if (bid < 6400) {
    int i = (bid - 2048) * 256 + threadIdx.x;
    if (i < 262144) w1b[i] = f2bf(w1[i]);
    int j = i - 262144;
    if (j >= 0 && j < 589824) {
      int co = j / 2304, rem = j % 2304;
      int d = rem >> 8, ci = rem & 255;
      w2b[j] = f2bf(w2[((size_t)(co * 256 + ci)) * 9 + d]);
    }
    int k = i - 851968;
    if (k >= 0 && k < 262144) w3b[k] = f2bf(w3[k]);
  } else {
    for (int k = threadIdx.x; k < 3136; k += 256) statszero[k] = 0.f;
  }
}

// ---------------- MFMA GEMM (R9 loop) + split-K ------------------------------
// Tile 128x128x64; 4 waves (2x2), per-wave 64x64, acc[4][4].
// Per K-tile: stage(next: 8 gloads); vmcnt(8); s_barrier; compute; s_barrier.
// SK>1: blockIdx.z = split; this block sums K-range [sk*K/SK,(sk+1)*K/SK) and
// writes raw f32 partials Pp[sk][m][Nc] (no bias/stats) -> k_reduce.
// SK==1: bias + bf16 store + BN-stats atomics in epilogue (as before).
// LDS read swizzle: row*128 + ((k16^(row&7))<<4); staging uses linear LDS
// dest + inverse-swizzled global source (rule #21).
static __device__ __forceinline__ int swz(int row, int k16) {
  return row * 128 + (((unsigned)(k16 ^ (row & 7))) << 4);
}

template <int MODE, int K, int SK>
__global__ __launch_bounds__(256) void gemm_kernel(const short* __restrict__ A,
                                                   const short* __restrict__ Bw,
                                                   const float* __restrict__ bias,
                                                   short* __restrict__ Yb,
                                                   float* __restrict__ Pp,
                                                   float* __restrict__ st,
                                                   int Nc,
                                                   const short* __restrict__ zerobuf) {
  __shared__ __align__(16) char lds[2][32768];  // per buf: A 16KB | B 16KB
  constexpr int NKT = K / 64 / SK;

  const int m0 = blockIdx.x * 128;
  const int n0 = blockIdx.y * 128;
  const int sk = (SK > 1) ? blockIdx.z : 0;
  const int kt0 = sk * NKT;
  const int t = threadIdx.x;
  const int lane = t & 63, wid = t >> 6;
  const int wm = wid >> 1, wn = wid & 1;
  const int g = lane >> 4, r = lane & 15;

  const short* aSrc[4];
  int aN[4], aH[4], aW[4], aCi[4];
  const short* bSrc[4];
#pragma unroll
  for (int q = 0; q < 4; ++q) {
    int chunk = t + q * 256;
    int row = chunk >> 3;
    int k16s = (chunk & 7) ^ (row & 7);
    if (MODE == 0) {
      aSrc[q] = A + (size_t)(m0 + row) * K + k16s * 8;
    } else {
      int m = m0 + row;
      int n_ = m / 196;
      int hw = m - n_ * 196;
      aN[q] = n_;
      aH[q] = hw / 14;
      aW[q] = hw - aH[q] * 14;
      aCi[q] = k16s * 8;
    }
    bSrc[q] = Bw + (size_t)(n0 + row) * K + k16s * 8;
  }

  auto stage = [&](int buf, int kt) {   // kt is GLOBAL K-tile index
    const int k0 = kt << 6;
    char* dA = &lds[buf][0];
    char* dB = &lds[buf][16384];
#pragma unroll
    for (int q = 0; q < 4; ++q) {
      const short* s;
      if (MODE == 0) {
        s = aSrc[q] + k0;
      } else {
        int d = kt >> 2;
        int dh = d / 3, dw = d - dh * 3;
        int hh = aH[q] + dh - 1, ww = aW[q] + dw - 1;
        s = ((unsigned)hh < 14u && (unsigned)ww < 14u)
                ? A + ((size_t)(aN[q] * 196 + hh * 14 + ww)) * 256 + (k0 & 255) + aCi[q]
                : zerobuf;
      }
      gload16(s, dA + (t + q * 256) * 16);
    }
#pragma unroll
    for (int q = 0; q < 4; ++q)
      gload16(bSrc[q] + k0, dB + (t + q * 256) * 16);
  };

  f32x4 acc[4][4] = {};
  auto compute = [&](int buf) {
    char* baseA = &lds[buf][0];
    char* baseB = &lds[buf][16384];
#pragma unroll
    for (int ks = 0; ks < 2; ++ks) {
      s16x8 af[4], bfr[4];
#pragma unroll
      for (int i = 0; i < 4; ++i)
        af[i] = *(const s16x8*)(baseA + swz(wm * 64 + i * 16 + r, ks * 4 + g));
#pragma unroll
      for (int j = 0; j < 4; ++j)
        bfr[j] = *(const s16x8*)(baseB + swz(wn * 64 + j * 16 + r, ks * 4 + g));
#pragma unroll
      for (int i = 0; i < 4; ++i)
#pragma unroll
        for (int j = 0; j < 4; ++j)
          acc[i][j] = __builtin_amdgcn_mfma_f32_16x16x32_bf16(af[i], bfr[j], acc[i][j], 0, 0, 0);
    }
  };

  stage(0, kt0);
  int cur = 0;
#pragma unroll 1
  for (int kti = 0; kti < NKT - 1; ++kti) {
    stage(cur ^ 1, kt0 + kti + 1);                     // 8 loads in flight
    asm volatile("s_waitcnt vmcnt(8)" ::: "memory");   // tile kti landed
    __builtin_amdgcn_s_barrier();
    compute(cur);
    asm volatile("" ::: "memory");
    __builtin_amdgcn_s_barrier();
    cur ^= 1;
  }
  asm volatile("s_waitcnt vmcnt(0)" ::: "memory");
  __builtin_amdgcn_s_barrier();
  compute(cur);

  if (SK == 1) {
    // epilogue: bias, bf16 store, per-channel sum/sumsq -> atomics
#pragma unroll
    for (int j = 0; j < 4; ++j) {
      int col = n0 + wn * 64 + j * 16 + r;
      float bv = bias[col];
      float ps = 0.f, pq = 0.f;
#pragma unroll
      for (int i = 0; i < 4; ++i) {
        int row_base = m0 + wm * 64 + i * 16 + g * 4;
#pragma unroll
        for (int rr = 0; rr < 4; ++rr) {
          float v = acc[i][j][rr] + bv;
          ps += v;
          pq += v * v;
          Yb[(size_t)(row_base + rr) * Nc + col] = f2bf(v);
        }
      }
      ps += __shfl_xor(ps, 16);
      ps += __shfl_xor(ps, 32);
      pq += __shfl_xor(pq, 16);
      pq += __shfl_xor(pq, 32);
      if (lane < 16) {
        atomicAdd(&st[col], ps);
        atomicAdd(&st[Nc + col], pq);
      }
    }
  } else {
    // raw f32 partials; k_reduce sums + bias + stats
#pragma unroll
    for (int j = 0; j < 4; ++j) {
      int col = n0 + wn * 64 + j * 16 + r;
#pragma unroll
      for (int i = 0; i < 4; ++i) {
        int row_base = m0 + wm * 64 + i * 16 + g * 4;
#pragma unroll
        for (int rr = 0; rr < 4; ++rr)
          Pp[((size_t)sk * MTOT + row_base + rr) * Nc + col] = acc[i][j][rr];
      }
    }
  }
}

// ----- reduce split-K partials: v = bias + sum_sk p; stats; bf16 store -------
template <int SKn>
__global__ __launch_bounds__(256) void k_reduce(const float* __restrict__ Pp,
                                                const float* __restrict__ bias,
                                                short* __restrict__ Yb,
                                                float* __restrict__ st) {
  const int t = threadIdx.x;  // channel
  const int r0 = blockIdx.x * 64;
  const float bv = bias[t];
  float s = 0.f, q = 0.f;
  for (int rr = 0; rr < 64; ++rr) {
    size_t row = r0 + rr;
    float v = bv;
#pragma unroll
    for (int sk = 0; sk < SKn; ++sk)
      v += Pp[((size_t)sk * MTOT + row) * 256 + t];
    s += v;
    q += v * v;
    Yb[row * 256 + t] = f2bf(v);
  }
  atomicAdd(&st[t], s);
  atomicAdd(&st[256 + t], q);
}

// ------- in-place: yb = bf16(relu(sc*yb+sh)), C=256; sc/sh computed here -----
__global__ __launch_bounds__(256) void k_apply(short* __restrict__ Yb,
                                               const float* __restrict__ st,
                                               const float* __restrict__ gamma,
                                               const float* __restrict__ beta) {
  __shared__ float lsc[256], lsh[256];
  const int t = threadIdx.x;
  {
    const float inv = 1.0f / 12544.0f;
    float mean = st[t] * inv;
    float var = st[256 + t] * inv - mean * mean;
    float s = gamma[t] * rsqrtf(var + 1e-5f);
    lsc[t] = s;
    lsh[t] = beta[t] - mean * s;
  }
  __syncthreads();
  size_t i8 = ((size_t)blockIdx.x * 256 + t) * 8;
  s16x8 v = *(const s16x8*)(Yb + i8);
  int c0 = (int)(i8 & 255);
#pragma unroll
  for (int e = 0; e < 8; ++e) {
    float f = bf2f(v[e]);
    v[e] = f2bf(fmaxf(lsc[c0 + e] * f + lsh[c0 + e], 0.f));
  }
  *(s16x8*)(Yb + i8) = v;
}

// -------- final: out = relu(x + softplus(rs)*bn3(y3)); sc/sh in-kernel -------
__global__ __launch_bounds__(256) void k_final(const float* __restrict__ x,
                                               const short* __restrict__ y3b,
                                               const float* __restrict__ st,
                                               const float* __restrict__ gamma,
                                               const float* __restrict__ beta,
                                               const float* __restrict__ rs,
                                               float* __restrict__ out) {
  __shared__ short ytile[64][198];
  __shared__ float lsc[64], lsh[64];
  const int n = blockIdx.x;
  const int co0 = blockIdx.y * 64;
  const int t = threadIdx.x;
  if (t < 64) {
    const float inv = 1.0f / 12544.0f;
    int c = co0 + t;
    float mean = st[c] * inv;
    float var = st[1024 + c] * inv - mean * mean;
    float s = gamma[c] * rsqrtf(var + 1e-5f);
    lsc[t] = s;
    lsh[t] = beta[c] - mean * s;
  }
#pragma unroll
  for (int iter = 0; iter < 49; ++iter) {
    int idx = iter * 256 + t;
    int hw = idx >> 6, c = idx & 63;
    ytile[c][hw] = y3b[((size_t)(n * 196 + hw)) * 1024 + co0 + c];
  }
  __syncthreads();
  float z = rs[0];
  float s = fmaxf(z, 0.f) + log1pf(expf(-fabsf(z)));  // stable softplus
#pragma unroll
  for (int iter = 0; iter < 49; ++iter) {
    int idx = iter * 256 + t;
    int co = idx / 196, hw = idx - co * 196;
    size_t xi = ((size_t)(n * 1024 + co0 + co)) * 196 + hw;
    float v = bf2f(ytile[co][hw]);
    float o = x[xi] + s * (lsc[co] * v + lsh[co]);
    out[xi] = fmaxf(o, 0.f);
  }
}

extern "C" void kernel_launch(void* const* d_in, const int* in_sizes, int n_in,
                              void* d_out, int out_size, void* d_ws, size_t ws_size,
                              hipStream_t stream) {
  const float* x   = (const float*)d_in[0];
  const float* w1  = (const float*)d_in[1];
  const float* b1  = (const float*)d_in[2];
  const float* g1  = (const float*)d_in[3];
  const float* be1 = (const float*)d_in[4];
  const float* w2  = (const float*)d_in[5];
  const float* b2  = (const float*)d_in[6];
  const float* g2  = (const float*)d_in[7];
  const float* be2 = (const float*)d_in[8];
  const float* w3  = (const float*)d_in[9];
  const float* b3  = (const float*)d_in[10];
  const float* g3  = (const float*)d_in[11];
  const float* be3 = (const float*)d_in[12];
  const float* rs  = (const float*)d_in[13];
  float* out = (float*)d_out;
  char* ws = (char*)d_ws;

  size_t off = 0;
  auto alloc = [&](size_t bytes) {
    size_t o = off;
    off += (bytes + 255) & ~(size_t)255;
    return o;
  };
  short* xb  = (short*)(ws + alloc((size_t)MTOT * CIN * 2));
  short* w1b = (short*)(ws + alloc((size_t)262144 * 2));
  short* w2b = (short*)(ws + alloc((size_t)589824 * 2));
  short* w3b = (short*)(ws + alloc((size_t)262144 * 2));
  short* y1b = (short*)(ws + alloc((size_t)MTOT * PL * 2));
  short* y2b = (short*)(ws + alloc((size_t)MTOT * PL * 2));
  short* y3b = (short*)(ws + alloc((size_t)MTOT * COUT * 2));
  float* Pp  = (float*)(ws + alloc((size_t)3 * MTOT * 256 * 4));  // 38.5 MB
  float* stats = (float*)(ws + alloc(12288 + 256));
  float* stat1 = stats, *stat2 = stats + 512, *stat3 = stats + 1024;
  short* zerobuf = (short*)(stats + 3072);

  k_prep<<<6401, 256, 0, stream>>>(x, w1, w2, w3, xb, w1b, w2b, w3b, stats);

  // conv1: 1x1 reduce (K=1024 -> 256), SK=2 -> 392 blocks
  gemm_kernel<0, 1024, 2><<<dim3(98, 2, 2), 256, 0, stream>>>(
      xb, w1b, b1, y1b, Pp, stat1, 256, zerobuf);
  k_reduce<2><<<196, 256, 0, stream>>>(Pp, b1, y1b, stat1);
  k_apply<<<1568, 256, 0, stream>>>(y1b, stat1, g1, be1);

  // conv2: 3x3 (K=2304 -> 256), SK=3 -> 588 blocks
  gemm_kernel<1, 2304, 3><<<dim3(98, 2, 3), 256, 0, stream>>>(
      y1b, w2b, b2, y2b, Pp, stat2, 256, zerobuf);
  k_reduce<3><<<196, 256, 0, stream>>>(Pp, b2, y2b, stat2);
  k_apply<<<1568, 256, 0, stream>>>(y2b, stat2, g2, be2);

  // conv3: 1x1 expand (K=256 -> 1024), SK=1, fused epilogue
  gemm_kernel<0, 256, 1><<<dim3(98, 8, 1), 256, 0, stream>>>(
      y2b, w3b, b3, y3b, Pp, stat3, 1024, zerobuf);

  // residual + relu (+ bn3 finalize in-kernel)
  k_final<<<dim3(64, 16), 256, 0, stream>>>(x, y3b, stat3, g3, be3, rs, out);
}

// Round 13
// 124.139 us; speedup vs baseline: 1.0921x; 1.0921x over previous
//
#include <hip/hip_runtime.h>
#include <hip/hip_bf16.h>
#include <cstdint>

#define NB   64
#define CIN  1024
#define HWSP 196
#define MTOT 12544
#define PL   256
#define COUT 1024

using f32x4 = __attribute__((ext_vector_type(4))) float;
using s16x8 = __attribute__((ext_vector_type(8))) short;

static __device__ __forceinline__ short f2bf(float f) {
  union { __hip_bfloat16 h; short s; } u;
  u.h = __float2bfloat16(f);
  return u.s;
}
static __device__ __forceinline__ float bf2f(short s) {
  union { float f; unsigned u; } x;
  x.u = ((unsigned)(unsigned short)s) << 16;
  return x.f;
}

static __device__ __forceinline__ void gload16(const void* g, void* l) {
  __builtin_amdgcn_global_load_lds((const __attribute__((address_space(1))) void*)g,
                                   (__attribute__((address_space(3))) void*)l, 16, 0, 0);
}

// ------------- merged prep: x-transpose | weight cast/reorder | stats zero ---
__global__ __launch_bounds__(256) void k_prep(const float* __restrict__ x,
                                              const float* __restrict__ w1,
                                              const float* __restrict__ w2,
                                              const float* __restrict__ w3,
                                              short* __restrict__ xb,
                                              short* __restrict__ w1b,
                                              short* __restrict__ w2b,
                                              short* __restrict__ w3b,
                                              float* __restrict__ statszero) {
  const int bid = blockIdx.x;
  if (bid < 2048) {
    __shared__ float tile[32][197];
    const int n = bid >> 5;
    const int c0 = (bid & 31) * 32;
    for (int idx = threadIdx.x; idx < 32 * 196; idx += 256) {
      int cl = idx / 196, hw = idx % 196;
      tile[cl][hw] = x[((size_t)(n * CIN + c0 + cl)) * HWSP + hw];
    }
    __syncthreads();
    for (int idx = threadIdx.x; idx < 196 * 32; idx += 256) {
      int hw = idx >> 5, cl = idx & 31;
      xb[((size_t)(n * HWSP + hw)) * CIN + c0 + cl] = f2bf(tile[cl][hw]);
    }
  } else if (bid < 6400) {
    int i = (bid - 2048) * 256 + threadIdx.x;
    if (i < 262144) w1b[i] = f2bf(w1[i]);
    int j = i - 262144;
    if (j >= 0 && j < 589824) {
      int co = j / 2304, rem = j % 2304;
      int d = rem >> 8, ci = rem & 255;
      w2b[j] = f2bf(w2[((size_t)(co * 256 + ci)) * 9 + d]);
    }
    int k = i - 851968;
    if (k >= 0 && k < 262144) w3b[k] = f2bf(w3[k]);
  } else {
    for (int k = threadIdx.x; k < 3136; k += 256) statszero[k] = 0.f;
  }
}

// ---------------- MFMA GEMM (R9 loop), BK templated --------------------------
// Tile 128x128xBK; 4 waves (2x2), per-wave 64x64, acc[4][4].
// Per K-tile: stage(next: 2*BK/16 gloads/thread); counted vmcnt; s_barrier;
// compute (BK/32 ks-steps); s_barrier. vmcnt never 0 until the last tile.
// LDS read swizzle: row*(2*BK) + ((k16 ^ (row&7)) << 4) — bijective within
// each row (XOR touches low 3 bits of the 16B-chunk index), <=2-way banks.
// Staging: linear LDS dest + inverse-swizzled global source (rule #21).
static __device__ __forceinline__ int swz(int row, int k16, int bk) {
  return row * (bk * 2) + (((unsigned)(k16 ^ (row & 7))) << 4);
}

template <int MODE, int K, int BK>
__global__ __launch_bounds__(256) void gemm_kernel(const short* __restrict__ A,
                                                   const short* __restrict__ Bw,
                                                   const float* __restrict__ bias,
                                                   short* __restrict__ Yb,
                                                   float* __restrict__ st,
                                                   int Nc,
                                                   const short* __restrict__ zerobuf) {
  constexpr int NKT = K / BK;
  constexpr int KCH = BK / 8;       // 16B chunks per row
  constexpr int QN = BK / 16;       // chunks per thread per matrix (4 or 8)
  constexpr int TBYTES = 128 * BK * 2;
  __shared__ __align__(16) char lds[2][2 * TBYTES];  // per buf: A | B

  const int m0 = blockIdx.x * 128;
  const int n0 = blockIdx.y * 128;
  const int t = threadIdx.x;
  const int lane = t & 63, wid = t >> 6;
  const int wm = wid >> 1, wn = wid & 1;
  const int g = lane >> 4, r = lane & 15;

  const short* aSrc[QN];
  int aN[QN], aH[QN], aW[QN], aCi[QN];
  const short* bSrc[QN];
#pragma unroll
  for (int q = 0; q < QN; ++q) {
    int chunk = t + q * 256;
    int row = chunk / KCH;
    int k16s = (chunk % KCH) ^ (row & 7);
    if (MODE == 0) {
      aSrc[q] = A + (size_t)(m0 + row) * K + k16s * 8;
    } else {
      int m = m0 + row;
      int n_ = m / 196;
      int hw = m - n_ * 196;
      aN[q] = n_;
      aH[q] = hw / 14;
      aW[q] = hw - aH[q] * 14;
      aCi[q] = k16s * 8;
    }
    bSrc[q] = Bw + (size_t)(n0 + row) * K + k16s * 8;
  }

  auto stage = [&](int buf, int kt) {
    const int k0 = kt * BK;
    char* dA = &lds[buf][0];
    char* dB = &lds[buf][TBYTES];
#pragma unroll
    for (int q = 0; q < QN; ++q) {
      const short* s;
      if (MODE == 0) {
        s = aSrc[q] + k0;
      } else {
        int d = k0 >> 8;
        int dh = d / 3, dw = d - dh * 3;
        int hh = aH[q] + dh - 1, ww = aW[q] + dw - 1;
        s = ((unsigned)hh < 14u && (unsigned)ww < 14u)
                ? A + ((size_t)(aN[q] * 196 + hh * 14 + ww)) * 256 + (k0 & 255) + aCi[q]
                : zerobuf;
      }
      gload16(s, dA + (t + q * 256) * 16);
    }
#pragma unroll
    for (int q = 0; q < QN; ++q)
      gload16(bSrc[q] + k0, dB + (t + q * 256) * 16);
  };

  f32x4 acc[4][4] = {};
  auto compute = [&](int buf) {
    char* baseA = &lds[buf][0];
    char* baseB = &lds[buf][TBYTES];
#pragma unroll
    for (int ks = 0; ks < BK / 32; ++ks) {
      s16x8 af[4], bfr[4];
#pragma unroll
      for (int i = 0; i < 4; ++i)
        af[i] = *(const s16x8*)(baseA + swz(wm * 64 + i * 16 + r, ks * 4 + g, BK));
#pragma unroll
      for (int j = 0; j < 4; ++j)
        bfr[j] = *(const s16x8*)(baseB + swz(wn * 64 + j * 16 + r, ks * 4 + g, BK));
#pragma unroll
      for (int i = 0; i < 4; ++i)
#pragma unroll
        for (int j = 0; j < 4; ++j)
          acc[i][j] = __builtin_amdgcn_mfma_f32_16x16x32_bf16(af[i], bfr[j], acc[i][j], 0, 0, 0);
    }
  };

  stage(0, 0);
  int cur = 0;
#pragma unroll 1
  for (int kt = 0; kt < NKT - 1; ++kt) {
    stage(cur ^ 1, kt + 1);                 // 2*QN loads in flight
    if constexpr (BK == 64)
      asm volatile("s_waitcnt vmcnt(8)" ::: "memory");
    else
      asm volatile("s_waitcnt vmcnt(16)" ::: "memory");
    __builtin_amdgcn_s_barrier();
    compute(cur);
    asm volatile("" ::: "memory");
    __builtin_amdgcn_s_barrier();
    cur ^= 1;
  }
  asm volatile("s_waitcnt vmcnt(0)" ::: "memory");
  __builtin_amdgcn_s_barrier();
  compute(cur);

  // epilogue: bias, bf16 store, per-channel sum/sumsq -> atomics
#pragma unroll
  for (int j = 0; j < 4; ++j) {
    int col = n0 + wn * 64 + j * 16 + r;
    float bv = bias[col];
    float ps = 0.f, pq = 0.f;
#pragma unroll
    for (int i = 0; i < 4; ++i) {
      int row_base = m0 + wm * 64 + i * 16 + g * 4;
#pragma unroll
      for (int rr = 0; rr < 4; ++rr) {
        float v = acc[i][j][rr] + bv;
        ps += v;
        pq += v * v;
        Yb[(size_t)(row_base + rr) * Nc + col] = f2bf(v);
      }
    }
    ps += __shfl_xor(ps, 16);
    ps += __shfl_xor(ps, 32);
    pq += __shfl_xor(pq, 16);
    pq += __shfl_xor(pq, 32);
    if (lane < 16) {
      atomicAdd(&st[col], ps);
      atomicAdd(&st[Nc + col], pq);
    }
  }
}

// ------- in-place: yb = bf16(relu(sc*yb+sh)), C=256; sc/sh computed here -----
__global__ __launch_bounds__(256) void k_apply(short* __restrict__ Yb,
                                               const float* __restrict__ st,
                                               const float* __restrict__ gamma,
                                               const float* __restrict__ beta) {
  __shared__ float lsc[256], lsh[256];
  const int t = threadIdx.x;
  {
    const float inv = 1.0f / 12544.0f;
    float mean = st[t] * inv;
    float var = st[256 + t] * inv - mean * mean;
    float s = gamma[t] * rsqrtf(var + 1e-5f);
    lsc[t] = s;
    lsh[t] = beta[t] - mean * s;
  }
  __syncthreads();
  size_t i8 = ((size_t)blockIdx.x * 256 + t) * 8;
  s16x8 v = *(const s16x8*)(Yb + i8);
  int c0 = (int)(i8 & 255);
#pragma unroll
  for (int e = 0; e < 8; ++e) {
    float f = bf2f(v[e]);
    v[e] = f2bf(fmaxf(lsc[c0 + e] * f + lsh[c0 + e], 0.f));
  }
  *(s16x8*)(Yb + i8) = v;
}

// -------- final: out = relu(x + softplus(rs)*bn3(y3)); sc/sh in-kernel -------
__global__ __launch_bounds__(256) void k_final(const float* __restrict__ x,
                                               const short* __restrict__ y3b,
                                               const float* __restrict__ st,
                                               const float* __restrict__ gamma,
                                               const float* __restrict__ beta,
                                               const float* __restrict__ rs,
                                               float* __restrict__ out) {
  __shared__ short ytile[64][198];
  __shared__ float lsc[64], lsh[64];
  const int n = blockIdx.x;
  const int co0 = blockIdx.y * 64;
  const int t = threadIdx.x;
  if (t < 64) {
    const float inv = 1.0f / 12544.0f;
    int c = co0 + t;
    float mean = st[c] * inv;
    float var = st[1024 + c] * inv - mean * mean;
    float s = gamma[c] * rsqrtf(var + 1e-5f);
    lsc[t] = s;
    lsh[t] = beta[c] - mean * s;
  }
#pragma unroll
  for (int iter = 0; iter < 49; ++iter) {
    int idx = iter * 256 + t;
    int hw = idx >> 6, c = idx & 63;
    ytile[c][hw] = y3b[((size_t)(n * 196 + hw)) * 1024 + co0 + c];
  }
  __syncthreads();
  float z = rs[0];
  float s = fmaxf(z, 0.f) + log1pf(expf(-fabsf(z)));  // stable softplus
#pragma unroll
  for (int iter = 0; iter < 49; ++iter) {
    int idx = iter * 256 + t;
    int co = idx / 196, hw = idx - co * 196;
    size_t xi = ((size_t)(n * 1024 + co0 + co)) * 196 + hw;
    float v = bf2f(ytile[co][hw]);
    float o = x[xi] + s * (lsc[co] * v + lsh[co]);
    out[xi] = fmaxf(o, 0.f);
  }
}

extern "C" void kernel_launch(void* const* d_in, const int* in_sizes, int n_in,
                              void* d_out, int out_size, void* d_ws, size_t ws_size,
                              hipStream_t stream) {
  const float* x   = (const float*)d_in[0];
  const float* w1  = (const float*)d_in[1];
  const float* b1  = (const float*)d_in[2];
  const float* g1  = (const float*)d_in[3];
  const float* be1 = (const float*)d_in[4];
  const float* w2  = (const float*)d_in[5];
  const float* b2  = (const float*)d_in[6];
  const float* g2  = (const float*)d_in[7];
  const float* be2 = (const float*)d_in[8];
  const float* w3  = (const float*)d_in[9];
  const float* b3  = (const float*)d_in[10];
  const float* g3  = (const float*)d_in[11];
  const float* be3 = (const float*)d_in[12];
  const float* rs  = (const float*)d_in[13];
  float* out = (float*)d_out;
  char* ws = (char*)d_ws;

  size_t off = 0;
  auto alloc = [&](size_t bytes) {
    size_t o = off;
    off += (bytes + 255) & ~(size_t)255;
    return o;
  };
  short* xb  = (short*)(ws + alloc((size_t)MTOT * CIN * 2));
  short* w1b = (short*)(ws + alloc((size_t)262144 * 2));
  short* w2b = (short*)(ws + alloc((size_t)589824 * 2));
  short* w3b = (short*)(ws + alloc((size_t)262144 * 2));
  short* y1b = (short*)(ws + alloc((size_t)MTOT * PL * 2));
  short* y2b = (short*)(ws + alloc((size_t)MTOT * PL * 2));
  short* y3b = (short*)(ws + alloc((size_t)MTOT * COUT * 2));
  float* stats = (float*)(ws + alloc(12288 + 256));
  float* stat1 = stats, *stat2 = stats + 512, *stat3 = stats + 1024;
  short* zerobuf = (short*)(stats + 3072);

  k_prep<<<6401, 256, 0, stream>>>(x, w1, w2, w3, xb, w1b, w2b, w3b, stats);

  // conv1: 1x1 reduce (K=1024 -> 256), BK=128 -> NKT=8
  gemm_kernel<0, 1024, 128><<<dim3(98, 2), 256, 0, stream>>>(xb, w1b, b1, y1b, stat1, 256, zerobuf);
  k_apply<<<1568, 256, 0, stream>>>(y1b, stat1, g1, be1);

  // conv2: 3x3 (K=2304 -> 256), BK=128 -> NKT=18
  gemm_kernel<1, 2304, 128><<<dim3(98, 2), 256, 0, stream>>>(y1b, w2b, b2, y2b, stat2, 256, zerobuf);
  k_apply<<<1568, 256, 0, stream>>>(y2b, stat2, g2, be2);

  // conv3: 1x1 expand (K=256 -> 1024), BK=64 (overlap-rich grid), NKT=4
  gemm_kernel<0, 256, 64><<<dim3(98, 8), 256, 0, stream>>>(y2b, w3b, b3, y3b, stat3, 1024, zerobuf);

  // residual + relu (+ bn3 finalize in-kernel)
  k_final<<<dim3(64, 16), 256, 0, stream>>>(x, y3b, stat3, g3, be3, rs, out);
}